// Round 2
// baseline (8908.565 us; speedup 1.0000x reference)
//
#include <hip/hip_runtime.h>

// ============================================================================
// CapsuleNet forward: conv1+relu -> conv2 -> squash -> dynamic routing (3 it)
// Round 2: fixed the round-1 abort (workspace overflow: 298 MB used).
//   - conv1 + conv2 + primary squash fused into one kernel (no h1/h2 buffers)
//   - routing 'b' logits eliminated via linearity: b_t = b_prior + uhat.(sum v)
//   - workspace now 46.3 MB (was 298 MB)
// All fp32 vector compute (no fp32 MFMA on CDNA4).
// ============================================================================

#define N_IMG 512

// ---------------------------------------------------------------------------
// repack conv2 weights [256 co][256 ci][81] -> wT[256 ci][81][256 co]
// (makes conv2's weight loads wave-coalesced)
// ---------------------------------------------------------------------------
__global__ void repack_kernel(const float* __restrict__ w2,
                              float* __restrict__ wT) {
  __shared__ float tile[64 * 81];
  const int ci = blockIdx.x;       // 0..255
  const int cb = blockIdx.y * 64;  // co block base
  for (int idx = threadIdx.x; idx < 64 * 81; idx += 256) {
    int col = idx / 81, k = idx % 81;
    tile[idx] = w2[((cb + col) * 256 + ci) * 81 + k];
  }
  __syncthreads();
  for (int idx = threadIdx.x; idx < 64 * 81; idx += 256) {
    int k = idx / 64, col = idx % 64;
    wT[(ci * 81 + k) * 256 + cb + col] = tile[col * 81 + k];
  }
}

// ---------------------------------------------------------------------------
// Fused conv1(+relu) -> conv2(+bias) -> primary capsule squash.
// 1 block / image (512 blocks = 2/CU), thread = conv2 output channel co.
// Per 32-input-channel chunk:
//   - conv1 computes the 32 channels' 20x20 maps into LDS tile (recompute
//     cost ~4% of conv2 FMAs), weights for the chunk staged in LDS.
//   - conv2 accumulates 36 outputs/thread from the tile (uniform-address
//     b128 broadcasts) and coalesced wT reads.
// Epilogue: bias, then squash across each group of 8 channels via LDS alias.
// LDS: 784 + 2592 + 32 + 12800 floats = 64.8 KB -> 2 blocks/CU.
// ---------------------------------------------------------------------------
__global__ __launch_bounds__(256, 2) void fused_conv_kernel(
    const float* __restrict__ x, const float* __restrict__ w1,
    const float* __restrict__ b1, const float* __restrict__ wT,
    const float* __restrict__ b2, float* __restrict__ u) {
  __shared__ float img[784];
  __shared__ float w1l[32 * 81];
  __shared__ float b1l[32];
  __shared__ float tile[32 * 400];  // aliased as sq[256*36] in the epilogue

  const int b = blockIdx.x;
  const int tid = threadIdx.x;
  const int co = tid;

  for (int i = tid; i < 784; i += 256) img[i] = x[b * 784 + i];

  float acc[36];
#pragma unroll
  for (int i = 0; i < 36; ++i) acc[i] = 0.0f;

  for (int cb = 0; cb < 256; cb += 32) {
    __syncthreads();  // prev iteration's conv2 reads of tile/w1l done
    for (int i = tid; i < 32 * 81; i += 256) {
      const int ch = i / 81, k = i % 81;
      w1l[i] = w1[(cb + ch) * 81 + k];
    }
    if (tid < 32) b1l[tid] = b1[cb + tid];
    __syncthreads();  // img (first iter) + w1l ready

    // conv1: task = oy*32 + ch  (640 tasks, 20 outputs each)
    for (int task = tid; task < 640; task += 256) {
      const int ch = task & 31;
      const int oy = task >> 5;
      float a[20];
      const float bv1 = b1l[ch];
#pragma unroll
      for (int ox = 0; ox < 20; ++ox) a[ox] = bv1;
#pragma unroll
      for (int r = 0; r < 9; ++r) {
        float row[28];
        const float4* rp = (const float4*)&img[(oy + r) * 28];
#pragma unroll
        for (int q = 0; q < 7; ++q) {
          float4 v4 = rp[q];
          row[4 * q + 0] = v4.x; row[4 * q + 1] = v4.y;
          row[4 * q + 2] = v4.z; row[4 * q + 3] = v4.w;
        }
#pragma unroll
        for (int s = 0; s < 9; ++s) {
          const float wval = w1l[ch * 81 + r * 9 + s];
#pragma unroll
          for (int ox = 0; ox < 20; ++ox)
            a[ox] = fmaf(row[ox + s], wval, a[ox]);
        }
      }
      float4* dst = (float4*)&tile[ch * 400 + oy * 20];
#pragma unroll
      for (int q = 0; q < 5; ++q) {
        float4 v4;
        v4.x = fmaxf(a[4 * q + 0], 0.0f);
        v4.y = fmaxf(a[4 * q + 1], 0.0f);
        v4.z = fmaxf(a[4 * q + 2], 0.0f);
        v4.w = fmaxf(a[4 * q + 3], 0.0f);
        dst[q] = v4;
      }
    }
    __syncthreads();  // tile ready

    // conv2 accumulation over this chunk's 32 input channels
    for (int c = 0; c < 32; ++c) {
      float wv[81];
#pragma unroll
      for (int k = 0; k < 81; ++k)
        wv[k] = wT[((cb + c) * 81 + k) * 256 + co];

#pragma unroll
      for (int iy = 0; iy < 19; ++iy) {
        float row[20];
        const float4* rp = (const float4*)&tile[c * 400 + iy * 20];
#pragma unroll
        for (int q = 0; q < 5; ++q) {
          float4 v4 = rp[q];
          row[4 * q + 0] = v4.x; row[4 * q + 1] = v4.y;
          row[4 * q + 2] = v4.z; row[4 * q + 3] = v4.w;
        }
#pragma unroll
        for (int oy = 0; oy < 6; ++oy) {
          const int r = iy - 2 * oy;  // compile-time per (iy,oy)
          if (r >= 0 && r < 9) {
#pragma unroll
            for (int s = 0; s < 9; ++s) {
              const float wval = wv[r * 9 + s];
#pragma unroll
              for (int ox = 0; ox < 6; ++ox)
                acc[oy * 6 + ox] = fmaf(row[2 * ox + s], wval, acc[oy * 6 + ox]);
            }
          }
        }
      }
    }
  }

  __syncthreads();  // all conv2 tile reads done; alias tile as sq
  float* sq = tile;  // 256*36 = 9216 floats <= 12800
  const float bv2 = b2[co];
#pragma unroll
  for (int i = 0; i < 36; ++i) sq[co * 36 + i] = acc[i] + bv2;
  __syncthreads();

  // primary squash: capsule i -> group g=i/36 (channels g*8..g*8+7), pos i%36
  for (int i = tid; i < 1152; i += 256) {
    const int g = i / 36, yx = i % 36;
    float vals[8];
    float lensq = 0.0f;
#pragma unroll
    for (int d = 0; d < 8; ++d) {
      vals[d] = sq[(g * 8 + d) * 36 + yx];
      lensq = fmaf(vals[d], vals[d], lensq);
    }
    const float len = sqrtf(lensq);
    const float scale = lensq / (1.0f + lensq) / len;
    float4* dst = (float4*)(u + ((size_t)b * 1152 + i) * 8);
    float4 lo, hi;
    lo.x = vals[0] * scale; lo.y = vals[1] * scale;
    lo.z = vals[2] * scale; lo.w = vals[3] * scale;
    hi.x = vals[4] * scale; hi.y = vals[5] * scale;
    hi.z = vals[6] * scale; hi.w = vals[7] * scale;
    dst[0] = lo; dst[1] = hi;
  }
}

// ---------------------------------------------------------------------------
// routing pass A: per (image b, capsule-chunk of 64):
//   recompute u_hat chunk (64x160) in LDS; b = b_prior (+ uhat.vsum for
//   pass>=1, by linearity of the logit update); softmax over o; partial
//   s -> s_part[chunk][b][160]. Grid is chunk-major so 512 consecutive
//   blocks share one 0.33 MB caps_w slice (L2-resident).
// ---------------------------------------------------------------------------
__global__ __launch_bounds__(256) void routing_a_kernel(
    const float* __restrict__ u, const float* __restrict__ caps_w,
    const float* __restrict__ b_prior, const float* __restrict__ vsum,
    float* __restrict__ s_part, int pass) {
  __shared__ float u_l[64 * 8];
  __shared__ float uhat[64 * 160];
  __shared__ float b_l[64 * 10];
  __shared__ float c_l[64 * 10];
  __shared__ float v_l[160];

  const int b = blockIdx.x;   // image
  const int ch = blockIdx.y;  // capsule chunk
  const int cap0 = ch * 64;
  const int tid = threadIdx.x;

  {
    const float* src = u + ((size_t)b * 1152 + cap0) * 8;
    for (int i = tid; i < 512; i += 256) u_l[i] = src[i];
  }
  if (pass > 0 && tid < 160) v_l[tid] = vsum[b * 160 + tid];
  __syncthreads();

  // u_hat[i][od] = sum_k u[i][k] * caps_w[cap0+i][k][od]
  for (int idx = tid; idx < 64 * 160; idx += 256) {
    const int i = idx / 160, od = idx % 160;
    const float* wp = caps_w + ((size_t)(cap0 + i)) * 1280 + od;
    float a = 0.0f;
#pragma unroll
    for (int k = 0; k < 8; ++k) a = fmaf(u_l[i * 8 + k], wp[k * 160], a);
    uhat[idx] = a;
  }
  __syncthreads();

  // b = b_prior (+ uhat . vsum)
  for (int idx = tid; idx < 640; idx += 256) {
    const int i = idx / 10, o = idx % 10;
    float bb = b_prior[(cap0 + i) * 10 + o];
    if (pass > 0) {
      float agg = 0.0f;
#pragma unroll
      for (int d = 0; d < 16; ++d)
        agg = fmaf(uhat[i * 160 + o * 16 + d], v_l[o * 16 + d], agg);
      bb += agg;
    }
    b_l[idx] = bb;
  }
  __syncthreads();

  // softmax over o (10) per capsule
  if (tid < 64) {
    float m = -1e30f;
#pragma unroll
    for (int o = 0; o < 10; ++o) m = fmaxf(m, b_l[tid * 10 + o]);
    float e[10], sum = 0.0f;
#pragma unroll
    for (int o = 0; o < 10; ++o) {
      e[o] = __expf(b_l[tid * 10 + o] - m);
      sum += e[o];
    }
    const float inv = 1.0f / sum;
#pragma unroll
    for (int o = 0; o < 10; ++o) c_l[tid * 10 + o] = e[o] * inv;
  }
  __syncthreads();

  // partial s over this chunk's 64 capsules
  if (tid < 160) {
    const int o = tid / 16;
    float a = 0.0f;
    for (int i = 0; i < 64; ++i)
      a = fmaf(c_l[i * 10 + o], uhat[i * 160 + tid], a);
    s_part[((size_t)ch * N_IMG + b) * 160 + tid] = a;
  }
}

// ---------------------------------------------------------------------------
// routing pass B: reduce 18 partials -> s[b][160]; squash -> v (d_out);
// probs = lensq/(1+lensq) = ||v||; vsum update per mode (0=set,1=add,2=none).
// ---------------------------------------------------------------------------
__global__ __launch_bounds__(192) void routing_b_kernel(
    const float* __restrict__ s_part, float* __restrict__ v_out,
    float* __restrict__ probs, float* __restrict__ vsum, int mode) {
  __shared__ float s_l[160];
  __shared__ float scale_l[10];
  __shared__ float len_l[10];
  const int b = blockIdx.x;
  const int t = threadIdx.x;
  if (t < 160) {
    float a = 0.0f;
#pragma unroll
    for (int ch = 0; ch < 18; ++ch)
      a += s_part[((size_t)ch * N_IMG + b) * 160 + t];
    s_l[t] = a;
  }
  __syncthreads();
  if (t < 10) {
    float lensq = 0.0f;
#pragma unroll
    for (int d = 0; d < 16; ++d) {
      const float xv = s_l[t * 16 + d];
      lensq = fmaf(xv, xv, lensq);
    }
    const float len = sqrtf(lensq);
    scale_l[t] = lensq / (1.0f + lensq) / len;
    len_l[t] = lensq / (1.0f + lensq);  // == ||v||
  }
  __syncthreads();
  if (t < 160) {
    const float vv = s_l[t] * scale_l[t / 16];
    v_out[b * 160 + t] = vv;
    if (mode == 0) vsum[b * 160 + t] = vv;
    else if (mode == 1) vsum[b * 160 + t] += vv;
  }
  if (t < 10) probs[b * 10 + t] = len_l[t];
}

// ===========================================================================
extern "C" void kernel_launch(void* const* d_in, const int* in_sizes, int n_in,
                              void* d_out, int out_size, void* d_ws,
                              size_t ws_size, hipStream_t stream) {
  const float* x  = (const float*)d_in[0];
  const float* w1 = (const float*)d_in[1];
  const float* b1 = (const float*)d_in[2];
  const float* w2 = (const float*)d_in[3];
  const float* b2 = (const float*)d_in[4];
  const float* cw = (const float*)d_in[5];
  const float* bp = (const float*)d_in[6];

  float* out = (float*)d_out;
  float* v_out = out;                // [512,10,16]
  float* probs = out + N_IMG * 160;  // [512,10]

  float* ws = (float*)d_ws;
  float* wT   = ws;  ws += (size_t)256 * 81 * 256;    // 21.2 MB
  float* u    = ws;  ws += (size_t)N_IMG * 1152 * 8;  // 18.9 MB
  float* sp   = ws;  ws += (size_t)18 * N_IMG * 160;  //  5.9 MB
  float* vsum = ws;  ws += (size_t)N_IMG * 160;       //  0.33 MB
                                                      // total 46.3 MB

  repack_kernel<<<dim3(256, 4), 256, 0, stream>>>(w2, wT);
  fused_conv_kernel<<<N_IMG, 256, 0, stream>>>(x, w1, b1, wT, b2, u);
  for (int pass = 0; pass < 4; ++pass) {
    const int mode = (pass == 0) ? 0 : (pass < 3 ? 1 : 2);
    routing_a_kernel<<<dim3(N_IMG, 18), 256, 0, stream>>>(u, cw, bp, vsum, sp,
                                                          pass);
    routing_b_kernel<<<N_IMG, 192, 0, stream>>>(sp, v_out, probs, vsum, mode);
  }
}

// Round 3
// 4250.280 us; speedup vs baseline: 2.0960x; 2.0960x over previous
//
#include <hip/hip_runtime.h>

// ============================================================================
// CapsuleNet forward: conv1+relu -> conv2 -> squash -> dynamic routing (3 it)
// Round 3: fused_conv was spill-bound (WRITE_SIZE 21.9 GB of scratch traffic,
// VALUBusy 27%). Fixes:
//   - conv2 inner loop: only 9 weights live (row-group) + explicit prefetch,
//     #pragma unroll 1 to keep register pressure down  -> no spills
//   - 2 images per block (512 thr, thread=(img,co)): halves wT re-read
//     traffic (10.9 GB -> 5.4 GB) and gives 2 waves/SIMD
// fp32 VALU compute floor for conv2 is ~1.25 ms.
// ============================================================================

#define N_IMG 512
#define CHUNK 16  // input channels staged in LDS per pass

// ---------------------------------------------------------------------------
// repack conv2 weights [256 co][256 ci][81] -> wT[256 ci][81][256 co]
// ---------------------------------------------------------------------------
__global__ void repack_kernel(const float* __restrict__ w2,
                              float* __restrict__ wT) {
  __shared__ float tile[64 * 81];
  const int ci = blockIdx.x;       // 0..255
  const int cb = blockIdx.y * 64;  // co block base
  for (int idx = threadIdx.x; idx < 64 * 81; idx += 256) {
    int col = idx / 81, k = idx % 81;
    tile[idx] = w2[((cb + col) * 256 + ci) * 81 + k];
  }
  __syncthreads();
  for (int idx = threadIdx.x; idx < 64 * 81; idx += 256) {
    int k = idx / 64, col = idx % 64;
    wT[(ci * 81 + k) * 256 + cb + col] = tile[col * 81 + k];
  }
}

// ---------------------------------------------------------------------------
// Fused conv1(+relu) -> conv2(+bias) -> primary capsule squash.
// 256 blocks x 512 threads; block = 2 images; thread = (img, co).
// Per 16-input-channel chunk: conv1 -> LDS tile; conv2 accumulates 36
// outputs/thread, weights loaded 9-at-a-time (no spills) with prefetch.
// LDS: 2*784 + 16*81 + 16 + 2*16*400 floats = 62.7 KB.
// ---------------------------------------------------------------------------
__global__ __launch_bounds__(512, 1) void fused_conv_kernel(
    const float* __restrict__ x, const float* __restrict__ w1,
    const float* __restrict__ b1, const float* __restrict__ wT,
    const float* __restrict__ b2, float* __restrict__ u) {
  __shared__ float img[2][784];
  __shared__ float w1l[CHUNK * 81];
  __shared__ float b1l[CHUNK];
  __shared__ float tile[2][CHUNK][400];

  const int bp = blockIdx.x;    // image pair
  const int tid = threadIdx.x;  // 0..511
  const int im = tid >> 8;      // this thread's image (wave-uniform)
  const int co = tid & 255;

  for (int i = tid; i < 2 * 784; i += 512) {
    const int ii = i / 784, p = i % 784;
    img[ii][p] = x[(bp * 2 + ii) * 784 + p];
  }

  float acc[36];
#pragma unroll
  for (int i = 0; i < 36; ++i) acc[i] = 0.0f;

  for (int cb = 0; cb < 256; cb += CHUNK) {
    __syncthreads();  // previous chunk's tile/w1l reads complete
    for (int i = tid; i < CHUNK * 81; i += 512) w1l[i] = w1[cb * 81 + i];
    if (tid < CHUNK) b1l[tid] = b1[cb + tid];
    __syncthreads();

    // conv1 into tile: task = (ig, oy, ch), 2*20*16 = 640 tasks
    for (int t = tid; t < 640; t += 512) {
      const int ch = t & 15;
      const int rest = t >> 4;        // 0..39
      const int oy = rest % 20;
      const int ig = rest / 20;
      float a[20];
      const float bv1 = b1l[ch];
#pragma unroll
      for (int ox = 0; ox < 20; ++ox) a[ox] = bv1;
#pragma unroll
      for (int r = 0; r < 9; ++r) {
        float row[28];
        const float4* rp = (const float4*)&img[ig][(oy + r) * 28];
#pragma unroll
        for (int q = 0; q < 7; ++q) {
          float4 v4 = rp[q];
          row[4 * q + 0] = v4.x; row[4 * q + 1] = v4.y;
          row[4 * q + 2] = v4.z; row[4 * q + 3] = v4.w;
        }
#pragma unroll
        for (int s = 0; s < 9; ++s) {
          const float wval = w1l[ch * 81 + r * 9 + s];
#pragma unroll
          for (int ox = 0; ox < 20; ++ox)
            a[ox] = fmaf(row[ox + s], wval, a[ox]);
        }
      }
      float4* dst = (float4*)&tile[ig][ch][oy * 20];
#pragma unroll
      for (int q = 0; q < 5; ++q) {
        float4 v4;
        v4.x = fmaxf(a[4 * q + 0], 0.0f);
        v4.y = fmaxf(a[4 * q + 1], 0.0f);
        v4.z = fmaxf(a[4 * q + 2], 0.0f);
        v4.w = fmaxf(a[4 * q + 3], 0.0f);
        dst[q] = v4;
      }
    }
    __syncthreads();  // tile ready

    // conv2: per input channel, weights in groups of 9 (one kernel row)
    for (int c = 0; c < CHUNK; ++c) {
      const float* wbase = wT + ((size_t)(cb + c) * 81) * 256 + co;
      const float* trow = &tile[im][c][0];
      float wv[9];
#pragma unroll
      for (int s = 0; s < 9; ++s) wv[s] = wbase[s * 256];

#pragma unroll 1
      for (int r = 0; r < 9; ++r) {
        float wn[9];
        if (r < 8) {  // prefetch next weight row; hidden under 324 FMAs
#pragma unroll
          for (int s = 0; s < 9; ++s) wn[s] = wbase[((r + 1) * 9 + s) * 256];
        }
#pragma unroll
        for (int oy = 0; oy < 6; ++oy) {
          const int iy = 2 * oy + r;  // 0..18
          float row[20];
          const float4* rp = (const float4*)&trow[iy * 20];
#pragma unroll
          for (int q = 0; q < 5; ++q) {
            float4 v4 = rp[q];
            row[4 * q + 0] = v4.x; row[4 * q + 1] = v4.y;
            row[4 * q + 2] = v4.z; row[4 * q + 3] = v4.w;
          }
#pragma unroll
          for (int s = 0; s < 9; ++s) {
            const float wval = wv[s];
#pragma unroll
            for (int ox = 0; ox < 6; ++ox)
              acc[oy * 6 + ox] = fmaf(row[2 * ox + s], wval, acc[oy * 6 + ox]);
          }
        }
        if (r < 8) {
#pragma unroll
          for (int s = 0; s < 9; ++s) wv[s] = wn[s];
        }
      }
    }
  }

  // epilogue: bias + squash, one image at a time through the tile buffer
  float* sq = &tile[0][0][0];  // 9216 floats needed, 12800 available
  const float bv2 = b2[co];
  for (int ig = 0; ig < 2; ++ig) {
    __syncthreads();  // conv2 tile reads (or prev img squash) complete
    if (im == ig) {
#pragma unroll
      for (int i = 0; i < 36; ++i) sq[co * 36 + i] = acc[i] + bv2;
    }
    __syncthreads();
    for (int i = tid; i < 1152; i += 512) {
      const int g = i / 36, yx = i % 36;
      float vals[8];
      float lensq = 0.0f;
#pragma unroll
      for (int d = 0; d < 8; ++d) {
        vals[d] = sq[(g * 8 + d) * 36 + yx];
        lensq = fmaf(vals[d], vals[d], lensq);
      }
      const float len = sqrtf(lensq);
      const float scale = lensq / (1.0f + lensq) / len;
      float4* dst = (float4*)(u + ((size_t)(bp * 2 + ig) * 1152 + i) * 8);
      float4 lo, hi;
      lo.x = vals[0] * scale; lo.y = vals[1] * scale;
      lo.z = vals[2] * scale; lo.w = vals[3] * scale;
      hi.x = vals[4] * scale; hi.y = vals[5] * scale;
      hi.z = vals[6] * scale; hi.w = vals[7] * scale;
      dst[0] = lo; dst[1] = hi;
    }
  }
}

// ---------------------------------------------------------------------------
// routing pass A: per (image b, capsule-chunk of 64):
//   recompute u_hat chunk (64x160) in LDS; b = b_prior (+ uhat.vsum for
//   pass>=1, by linearity of the logit update); softmax over o; partial
//   s -> s_part[chunk][b][160].
// ---------------------------------------------------------------------------
__global__ __launch_bounds__(256) void routing_a_kernel(
    const float* __restrict__ u, const float* __restrict__ caps_w,
    const float* __restrict__ b_prior, const float* __restrict__ vsum,
    float* __restrict__ s_part, int pass) {
  __shared__ float u_l[64 * 8];
  __shared__ float uhat[64 * 160];
  __shared__ float b_l[64 * 10];
  __shared__ float c_l[64 * 10];
  __shared__ float v_l[160];

  const int b = blockIdx.x;   // image
  const int ch = blockIdx.y;  // capsule chunk
  const int cap0 = ch * 64;
  const int tid = threadIdx.x;

  {
    const float* src = u + ((size_t)b * 1152 + cap0) * 8;
    for (int i = tid; i < 512; i += 256) u_l[i] = src[i];
  }
  if (pass > 0 && tid < 160) v_l[tid] = vsum[b * 160 + tid];
  __syncthreads();

  for (int idx = tid; idx < 64 * 160; idx += 256) {
    const int i = idx / 160, od = idx % 160;
    const float* wp = caps_w + ((size_t)(cap0 + i)) * 1280 + od;
    float a = 0.0f;
#pragma unroll
    for (int k = 0; k < 8; ++k) a = fmaf(u_l[i * 8 + k], wp[k * 160], a);
    uhat[idx] = a;
  }
  __syncthreads();

  for (int idx = tid; idx < 640; idx += 256) {
    const int i = idx / 10, o = idx % 10;
    float bb = b_prior[(cap0 + i) * 10 + o];
    if (pass > 0) {
      float agg = 0.0f;
#pragma unroll
      for (int d = 0; d < 16; ++d)
        agg = fmaf(uhat[i * 160 + o * 16 + d], v_l[o * 16 + d], agg);
      bb += agg;
    }
    b_l[idx] = bb;
  }
  __syncthreads();

  if (tid < 64) {
    float m = -1e30f;
#pragma unroll
    for (int o = 0; o < 10; ++o) m = fmaxf(m, b_l[tid * 10 + o]);
    float e[10], sum = 0.0f;
#pragma unroll
    for (int o = 0; o < 10; ++o) {
      e[o] = __expf(b_l[tid * 10 + o] - m);
      sum += e[o];
    }
    const float inv = 1.0f / sum;
#pragma unroll
    for (int o = 0; o < 10; ++o) c_l[tid * 10 + o] = e[o] * inv;
  }
  __syncthreads();

  if (tid < 160) {
    const int o = tid / 16;
    float a = 0.0f;
    for (int i = 0; i < 64; ++i)
      a = fmaf(c_l[i * 10 + o], uhat[i * 160 + tid], a);
    s_part[((size_t)ch * N_IMG + b) * 160 + tid] = a;
  }
}

// ---------------------------------------------------------------------------
// routing pass B: reduce 18 partials -> s[b][160]; squash -> v (d_out);
// probs; vsum update per mode (0=set,1=add,2=none).
// ---------------------------------------------------------------------------
__global__ __launch_bounds__(192) void routing_b_kernel(
    const float* __restrict__ s_part, float* __restrict__ v_out,
    float* __restrict__ probs, float* __restrict__ vsum, int mode) {
  __shared__ float s_l[160];
  __shared__ float scale_l[10];
  __shared__ float len_l[10];
  const int b = blockIdx.x;
  const int t = threadIdx.x;
  if (t < 160) {
    float a = 0.0f;
#pragma unroll
    for (int ch = 0; ch < 18; ++ch)
      a += s_part[((size_t)ch * N_IMG + b) * 160 + t];
    s_l[t] = a;
  }
  __syncthreads();
  if (t < 10) {
    float lensq = 0.0f;
#pragma unroll
    for (int d = 0; d < 16; ++d) {
      const float xv = s_l[t * 16 + d];
      lensq = fmaf(xv, xv, lensq);
    }
    const float len = sqrtf(lensq);
    scale_l[t] = lensq / (1.0f + lensq) / len;
    len_l[t] = lensq / (1.0f + lensq);  // == ||v||
  }
  __syncthreads();
  if (t < 160) {
    const float vv = s_l[t] * scale_l[t / 16];
    v_out[b * 160 + t] = vv;
    if (mode == 0) vsum[b * 160 + t] = vv;
    else if (mode == 1) vsum[b * 160 + t] += vv;
  }
  if (t < 10) probs[b * 10 + t] = len_l[t];
}

// ===========================================================================
extern "C" void kernel_launch(void* const* d_in, const int* in_sizes, int n_in,
                              void* d_out, int out_size, void* d_ws,
                              size_t ws_size, hipStream_t stream) {
  const float* x  = (const float*)d_in[0];
  const float* w1 = (const float*)d_in[1];
  const float* b1 = (const float*)d_in[2];
  const float* w2 = (const float*)d_in[3];
  const float* b2 = (const float*)d_in[4];
  const float* cw = (const float*)d_in[5];
  const float* bp = (const float*)d_in[6];

  float* out = (float*)d_out;
  float* v_out = out;                // [512,10,16]
  float* probs = out + N_IMG * 160;  // [512,10]

  float* ws = (float*)d_ws;
  float* wT   = ws;  ws += (size_t)256 * 81 * 256;    // 21.2 MB
  float* u    = ws;  ws += (size_t)N_IMG * 1152 * 8;  // 18.9 MB
  float* sp   = ws;  ws += (size_t)18 * N_IMG * 160;  //  5.9 MB
  float* vsum = ws;  ws += (size_t)N_IMG * 160;       //  0.33 MB

  repack_kernel<<<dim3(256, 4), 256, 0, stream>>>(w2, wT);
  fused_conv_kernel<<<N_IMG / 2, 512, 0, stream>>>(x, w1, b1, wT, b2, u);
  for (int pass = 0; pass < 4; ++pass) {
    const int mode = (pass == 0) ? 0 : (pass < 3 ? 1 : 2);
    routing_a_kernel<<<dim3(N_IMG, 18), 256, 0, stream>>>(u, cw, bp, vsum, sp,
                                                          pass);
    routing_b_kernel<<<N_IMG, 192, 0, stream>>>(sp, v_out, probs, vsum, mode);
  }
}

// Round 4
// 1378.130 us; speedup vs baseline: 6.4642x; 3.0841x over previous
//
#include <hip/hip_runtime.h>

// ============================================================================
// CapsuleNet forward: conv1+relu -> conv2 -> squash -> dynamic routing (3 it)
// Round 4: conv2 moved from fp32 VALU (4.2 ms, VALU-issue-bound) to bf16
// hi/lo-split MFMA implicit GEMM (error ~2^-17, fp32 accum):
//   C = Ah*Bh + Ah*Bl + Al*Bh   (Al*Bl dropped)
// Block = 2 images: conv1 (fp32, LDS) -> hi/lo bf16 A-tile in LDS ->
// 16x16x32 bf16 MFMA over K = (9*9 rs padded to 82) * 256 ci.
// B (conv2 weights) pre-repacked into MFMA B-fragment order, streamed from
// L2 (per-XCD lockstep reuse).
// ============================================================================

#define N_IMG 512

typedef __attribute__((ext_vector_type(8))) short bf16x8;
typedef __attribute__((ext_vector_type(4))) float f32x4;
typedef __attribute__((ext_vector_type(4))) unsigned int u32x4;

__device__ __forceinline__ unsigned short f2bf(float v) {
  unsigned int uu = __float_as_uint(v);
  uu += 0x7FFF + ((uu >> 16) & 1);
  return (unsigned short)(uu >> 16);
}
__device__ __forceinline__ float bf2f(unsigned short h) {
  return __uint_as_float(((unsigned int)h) << 16);
}

// ---------------------------------------------------------------------------
// repack conv2 weights w2[256 co][256 ci][81 rs] -> B-fragment order, hi/lo:
// Bp[ntile 16][ktile 656][lane 64][8 bf16]
// ktile = c*41 + tt (c = ci-chunk of 16, tt = 0..40 over k' = rs*16+cio,
// rs padded to 82 with zeros). lane: col = n*16+(lane&15),
// k-group = (lane>>4)*8 -> rs = 2*tt + (lane>>5), cio = ((lane>>4)&1)*8 + j.
// ---------------------------------------------------------------------------
__global__ __launch_bounds__(256) void repack_b_kernel(
    const float* __restrict__ w2, unsigned short* __restrict__ bph,
    unsigned short* __restrict__ bpl) {
  const int n = blockIdx.x;
  const int c = blockIdx.y;
  const int lane = threadIdx.x & 63;
  const int co = n * 16 + (lane & 15);
  const int lh = lane >> 5;
  const int cio8 = ((lane >> 4) & 1) * 8;
  for (int tt = (threadIdx.x >> 6); tt < 41; tt += 4) {
    const int rs = 2 * tt + lh;
    unsigned int hw[4], lw[4];
#pragma unroll
    for (int jp = 0; jp < 4; ++jp) {
      unsigned short h2[2], l2[2];
#pragma unroll
      for (int e = 0; e < 2; ++e) {
        const int j = jp * 2 + e;
        const int ci = c * 16 + cio8 + j;
        float v = (rs < 81) ? w2[((size_t)co * 256 + ci) * 81 + rs] : 0.0f;
        unsigned short hh = f2bf(v);
        h2[e] = hh;
        l2[e] = f2bf(v - bf2f(hh));
      }
      hw[jp] = (unsigned int)h2[0] | ((unsigned int)h2[1] << 16);
      lw[jp] = (unsigned int)l2[0] | ((unsigned int)l2[1] << 16);
    }
    const size_t off = (((size_t)n * 656 + c * 41 + tt) * 64 + lane) * 8;
    u32x4 hv = {hw[0], hw[1], hw[2], hw[3]};
    u32x4 lv = {lw[0], lw[1], lw[2], lw[3]};
    *(u32x4*)(bph + off) = hv;
    *(u32x4*)(bpl + off) = lv;
  }
}

// ---------------------------------------------------------------------------
// Fused conv1 -> hi/lo A-tile -> MFMA conv2 -> bias -> primary squash.
// 256 blocks x 512 threads (8 waves); block = 2 images (M=72 pad 80).
// LDS (floats): Ah 9612 | Al 9612 | stg 12928 | img 1568 | w1l 1296 | b1l 16
//   = 35032 f = 140.1 KB. sq[2*256*36] aliases Ah/Al in the epilogue.
// A-tile rows: row = img*400 + pos (pos=iy*20+ix), 48 B/row (16 bf16 + pad),
// row 800 = zeros (M-pad and rs-pad reads land there).
// ---------------------------------------------------------------------------
__global__ __launch_bounds__(512, 1) void fused_conv_kernel(
    const float* __restrict__ x, const float* __restrict__ w1,
    const float* __restrict__ b1, const unsigned short* __restrict__ bph,
    const unsigned short* __restrict__ bpl, const float* __restrict__ b2,
    float* __restrict__ u) {
  __shared__ __align__(16) float smem[35032];
  unsigned short* AhU = (unsigned short*)smem;  // 801 rows * 24 ushorts
  float* stg = smem + 19224;                    // [2][16][404]
  float* img = smem + 32152;                    // [2][784]
  float* w1l = smem + 33720;                    // [16*81]
  float* b1l = smem + 35016;                    // [16]
  float* sq = smem;                             // epilogue alias [2*256*36]

  const int bp2 = blockIdx.x;  // image pair
  const int tid = threadIdx.x;
  const int wid = tid >> 6;
  const int lane = tid & 63;
  const int l15 = lane & 15;
  const int lq = lane >> 4;
  const int lh = lane >> 5;
  const int cio_byte = (lq & 1) * 16;
  const int zoff = 800 * 48 + cio_byte;

  // per-mtile A row-address bases (byte offsets into AhU, incl. cio select)
  int rowAddr[5];
  bool mvalid[5];
#pragma unroll
  for (int mt = 0; mt < 5; ++mt) {
    const int m = mt * 16 + l15;
    mvalid[mt] = (m < 72);
    const int mm = mvalid[mt] ? m : 0;
    const int im = (mm >= 36) ? 1 : 0;
    const int p = mm - 36 * im;
    const int oy = p / 6, ox = p - 6 * oy;
    rowAddr[mt] = (im * 400 + 40 * oy + 2 * ox) * 48 + cio_byte;
  }

  const int n0 = 2 * wid;

  for (int i = tid; i < 1568; i += 512) img[i] = x[bp2 * 1568 + i];
  if (tid < 24) {  // zero row 800 of Ah and Al
    AhU[800 * 24 + tid] = 0;
    AhU[9612 * 2 + 800 * 24 + tid] = 0;
  }

  f32x4 acc[5][2];
#pragma unroll
  for (int mt = 0; mt < 5; ++mt)
#pragma unroll
    for (int nt = 0; nt < 2; ++nt) acc[mt][nt] = (f32x4){0.f, 0.f, 0.f, 0.f};

  for (int c = 0; c < 16; ++c) {
    __syncthreads();  // prev chunk's MFMA reads (or initial stores) done
    for (int i = tid; i < 1296; i += 512) w1l[i] = w1[c * 1296 + i];
    if (tid < 16) b1l[tid] = b1[c * 16 + tid];
    __syncthreads();

    // conv1: 640 tasks = (ig, oy, ch); each computes one 20-wide output row
    for (int t = tid; t < 640; t += 512) {
      const int ig = t / 320;
      const int rest = t - ig * 320;
      const int ch = rest & 15;
      const int oy = rest >> 4;
      const float* ib = &img[ig * 784];
      float a[20];
      const float bv1 = b1l[ch];
#pragma unroll
      for (int ox = 0; ox < 20; ++ox) a[ox] = bv1;
#pragma unroll
      for (int r = 0; r < 9; ++r) {
        float row[28];
        const float4* rp = (const float4*)&ib[(oy + r) * 28];
#pragma unroll
        for (int q = 0; q < 7; ++q) {
          float4 v4 = rp[q];
          row[4 * q + 0] = v4.x; row[4 * q + 1] = v4.y;
          row[4 * q + 2] = v4.z; row[4 * q + 3] = v4.w;
        }
#pragma unroll
        for (int s = 0; s < 9; ++s) {
          const float wval = w1l[ch * 81 + r * 9 + s];
#pragma unroll
          for (int ox = 0; ox < 20; ++ox)
            a[ox] = fmaf(row[ox + s], wval, a[ox]);
        }
      }
      float4* dst = (float4*)&stg[(ig * 16 + ch) * 404 + oy * 20];
#pragma unroll
      for (int q = 0; q < 5; ++q) {
        float4 v4;
        v4.x = fmaxf(a[4 * q + 0], 0.0f);
        v4.y = fmaxf(a[4 * q + 1], 0.0f);
        v4.z = fmaxf(a[4 * q + 2], 0.0f);
        v4.w = fmaxf(a[4 * q + 3], 0.0f);
        dst[q] = v4;
      }
    }
    __syncthreads();

    // transpose to A-layout: 800 tasks = (ig, pos); 16 ci -> hi/lo bf16
    for (int t = tid; t < 800; t += 512) {
      const int ig = t / 400;
      const int pos = t - ig * 400;
      const int row = ig * 400 + pos;
      unsigned int hw[8], lw[8];
#pragma unroll
      for (int jp = 0; jp < 8; ++jp) {
        unsigned short h2[2], l2[2];
#pragma unroll
        for (int e = 0; e < 2; ++e) {
          const float v = stg[(ig * 16 + jp * 2 + e) * 404 + pos];
          const unsigned short hh = f2bf(v);
          h2[e] = hh;
          l2[e] = f2bf(v - bf2f(hh));
        }
        hw[jp] = (unsigned int)h2[0] | ((unsigned int)h2[1] << 16);
        lw[jp] = (unsigned int)l2[0] | ((unsigned int)l2[1] << 16);
      }
      u32x4* dh = (u32x4*)(AhU + row * 24);
      u32x4* dl = (u32x4*)(AhU + 9612 * 2 + row * 24);
      dh[0] = (u32x4){hw[0], hw[1], hw[2], hw[3]};
      dh[1] = (u32x4){hw[4], hw[5], hw[6], hw[7]};
      dl[0] = (u32x4){lw[0], lw[1], lw[2], lw[3]};
      dl[1] = (u32x4){lw[4], lw[5], lw[6], lw[7]};
    }
    __syncthreads();

    // MFMA phase: 41 k-steps of 32 over this chunk
    const unsigned short* pb0 = bph + (((size_t)n0 * 656) + c * 41) * 512 + lane * 8;
    const unsigned short* pl0 = bpl + (((size_t)n0 * 656) + c * 41) * 512 + lane * 8;
    const unsigned short* pb1 = pb0 + 656 * 512;
    const unsigned short* pl1 = pl0 + 656 * 512;
    for (int tt = 0; tt < 41; ++tt) {
      const int rs = 2 * tt + lh;
      const int r = (rs * 57) >> 9;
      const int s = rs - 9 * r;
      const int offb = 960 * r + 48 * s;  // (20r+s)*48
      const bool vrs = rs < 81;

      const bf16x8 bh0 = *(const bf16x8*)(pb0 + (size_t)tt * 512);
      const bf16x8 bl0 = *(const bf16x8*)(pl0 + (size_t)tt * 512);
      const bf16x8 bh1 = *(const bf16x8*)(pb1 + (size_t)tt * 512);
      const bf16x8 bl1 = *(const bf16x8*)(pl1 + (size_t)tt * 512);

      bf16x8 ah[5], al[5];
#pragma unroll
      for (int mt = 0; mt < 5; ++mt) {
        const int ab = (mvalid[mt] && vrs) ? (rowAddr[mt] + offb) : zoff;
        ah[mt] = *(const bf16x8*)((const char*)AhU + ab);
        al[mt] = *(const bf16x8*)((const char*)AhU + 9612 * 4 + ab);
      }
#pragma unroll
      for (int mt = 0; mt < 5; ++mt) {
        acc[mt][0] = __builtin_amdgcn_mfma_f32_16x16x32_bf16(al[mt], bh0, acc[mt][0], 0, 0, 0);
        acc[mt][0] = __builtin_amdgcn_mfma_f32_16x16x32_bf16(ah[mt], bl0, acc[mt][0], 0, 0, 0);
        acc[mt][0] = __builtin_amdgcn_mfma_f32_16x16x32_bf16(ah[mt], bh0, acc[mt][0], 0, 0, 0);
        acc[mt][1] = __builtin_amdgcn_mfma_f32_16x16x32_bf16(al[mt], bh1, acc[mt][1], 0, 0, 0);
        acc[mt][1] = __builtin_amdgcn_mfma_f32_16x16x32_bf16(ah[mt], bl1, acc[mt][1], 0, 0, 0);
        acc[mt][1] = __builtin_amdgcn_mfma_f32_16x16x32_bf16(ah[mt], bh1, acc[mt][1], 0, 0, 0);
      }
    }
  }

  // epilogue: C -> sq (bias), then primary squash -> u
  __syncthreads();
  float b2v[2];
  b2v[0] = b2[n0 * 16 + l15];
  b2v[1] = b2[(n0 + 1) * 16 + l15];
#pragma unroll
  for (int mt = 0; mt < 5; ++mt) {
#pragma unroll
    for (int i = 0; i < 4; ++i) {
      const int m = mt * 16 + lq * 4 + i;
      if (m < 72) {
        const int im = (m >= 36) ? 1 : 0;
        const int p36 = m - 36 * im;
#pragma unroll
        for (int nt = 0; nt < 2; ++nt) {
          sq[(im * 256 + (n0 + nt) * 16 + l15) * 36 + p36] =
              acc[mt][nt][i] + b2v[nt];
        }
      }
    }
  }
  __syncthreads();

  for (int i = tid; i < 2304; i += 512) {
    const int ig = i / 1152;
    const int cap = i - ig * 1152;
    const int g = cap / 36, yx = cap - 36 * g;
    float vals[8];
    float lensq = 0.0f;
#pragma unroll
    for (int d = 0; d < 8; ++d) {
      vals[d] = sq[(ig * 256 + g * 8 + d) * 36 + yx];
      lensq = fmaf(vals[d], vals[d], lensq);
    }
    const float len = sqrtf(lensq);
    const float scale = lensq / (1.0f + lensq) / len;
    float4* dst = (float4*)(u + ((size_t)(bp2 * 2 + ig) * 1152 + cap) * 8);
    float4 lo4, hi4;
    lo4.x = vals[0] * scale; lo4.y = vals[1] * scale;
    lo4.z = vals[2] * scale; lo4.w = vals[3] * scale;
    hi4.x = vals[4] * scale; hi4.y = vals[5] * scale;
    hi4.z = vals[6] * scale; hi4.w = vals[7] * scale;
    dst[0] = lo4; dst[1] = hi4;
  }
}

// ---------------------------------------------------------------------------
// routing pass A (unchanged): per (image, capsule-chunk of 64): recompute
// u_hat (64x160) in LDS; b = b_prior (+ uhat.vsum, linearity); softmax;
// partial s -> s_part.
// ---------------------------------------------------------------------------
__global__ __launch_bounds__(256) void routing_a_kernel(
    const float* __restrict__ u, const float* __restrict__ caps_w,
    const float* __restrict__ b_prior, const float* __restrict__ vsum,
    float* __restrict__ s_part, int pass) {
  __shared__ float u_l[64 * 8];
  __shared__ float uhat[64 * 160];
  __shared__ float b_l[64 * 10];
  __shared__ float c_l[64 * 10];
  __shared__ float v_l[160];

  const int b = blockIdx.x;
  const int ch = blockIdx.y;
  const int cap0 = ch * 64;
  const int tid = threadIdx.x;

  {
    const float* src = u + ((size_t)b * 1152 + cap0) * 8;
    for (int i = tid; i < 512; i += 256) u_l[i] = src[i];
  }
  if (pass > 0 && tid < 160) v_l[tid] = vsum[b * 160 + tid];
  __syncthreads();

  for (int idx = tid; idx < 64 * 160; idx += 256) {
    const int i = idx / 160, od = idx - 160 * i;
    const float* wp = caps_w + ((size_t)(cap0 + i)) * 1280 + od;
    float a = 0.0f;
#pragma unroll
    for (int k = 0; k < 8; ++k) a = fmaf(u_l[i * 8 + k], wp[k * 160], a);
    uhat[idx] = a;
  }
  __syncthreads();

  for (int idx = tid; idx < 640; idx += 256) {
    const int i = idx / 10, o = idx - 10 * i;
    float bb = b_prior[(cap0 + i) * 10 + o];
    if (pass > 0) {
      float agg = 0.0f;
#pragma unroll
      for (int d = 0; d < 16; ++d)
        agg = fmaf(uhat[i * 160 + o * 16 + d], v_l[o * 16 + d], agg);
      bb += agg;
    }
    b_l[idx] = bb;
  }
  __syncthreads();

  if (tid < 64) {
    float m = -1e30f;
#pragma unroll
    for (int o = 0; o < 10; ++o) m = fmaxf(m, b_l[tid * 10 + o]);
    float e[10], sum = 0.0f;
#pragma unroll
    for (int o = 0; o < 10; ++o) {
      e[o] = __expf(b_l[tid * 10 + o] - m);
      sum += e[o];
    }
    const float inv = 1.0f / sum;
#pragma unroll
    for (int o = 0; o < 10; ++o) c_l[tid * 10 + o] = e[o] * inv;
  }
  __syncthreads();

  if (tid < 160) {
    const int o = tid / 16;
    float a = 0.0f;
    for (int i = 0; i < 64; ++i)
      a = fmaf(c_l[i * 10 + o], uhat[i * 160 + tid], a);
    s_part[((size_t)ch * N_IMG + b) * 160 + tid] = a;
  }
}

// ---------------------------------------------------------------------------
// routing pass B (unchanged): reduce partials -> squash -> v, probs, vsum.
// ---------------------------------------------------------------------------
__global__ __launch_bounds__(192) void routing_b_kernel(
    const float* __restrict__ s_part, float* __restrict__ v_out,
    float* __restrict__ probs, float* __restrict__ vsum, int mode) {
  __shared__ float s_l[160];
  __shared__ float scale_l[10];
  __shared__ float len_l[10];
  const int b = blockIdx.x;
  const int t = threadIdx.x;
  if (t < 160) {
    float a = 0.0f;
#pragma unroll
    for (int ch = 0; ch < 18; ++ch)
      a += s_part[((size_t)ch * N_IMG + b) * 160 + t];
    s_l[t] = a;
  }
  __syncthreads();
  if (t < 10) {
    float lensq = 0.0f;
#pragma unroll
    for (int d = 0; d < 16; ++d) {
      const float xv = s_l[t * 16 + d];
      lensq = fmaf(xv, xv, lensq);
    }
    const float len = sqrtf(lensq);
    scale_l[t] = lensq / (1.0f + lensq) / len;
    len_l[t] = lensq / (1.0f + lensq);
  }
  __syncthreads();
  if (t < 160) {
    const float vv = s_l[t] * scale_l[t / 16];
    v_out[b * 160 + t] = vv;
    if (mode == 0) vsum[b * 160 + t] = vv;
    else if (mode == 1) vsum[b * 160 + t] += vv;
  }
  if (t < 10) probs[b * 10 + t] = len_l[t];
}

// ===========================================================================
extern "C" void kernel_launch(void* const* d_in, const int* in_sizes, int n_in,
                              void* d_out, int out_size, void* d_ws,
                              size_t ws_size, hipStream_t stream) {
  const float* x  = (const float*)d_in[0];
  const float* w1 = (const float*)d_in[1];
  const float* b1 = (const float*)d_in[2];
  const float* w2 = (const float*)d_in[3];
  const float* b2 = (const float*)d_in[4];
  const float* cw = (const float*)d_in[5];
  const float* bp = (const float*)d_in[6];

  float* out = (float*)d_out;
  float* v_out = out;                // [512,10,16]
  float* probs = out + N_IMG * 160;  // [512,10]

  float* ws = (float*)d_ws;
  unsigned short* bph = (unsigned short*)ws;              // 10.25 MiB
  unsigned short* bpl = bph + (size_t)16 * 656 * 512;     // 10.25 MiB
  float* u    = ws + 2 * 2686976;                         // 18.9 MB
  float* sp   = u + (size_t)N_IMG * 1152 * 8;             //  5.9 MB
  float* vsum = sp + (size_t)18 * N_IMG * 160;            //  0.33 MB
                                                          // total ~45.6 MB

  repack_b_kernel<<<dim3(16, 16), 256, 0, stream>>>(w2, bph, bpl);
  fused_conv_kernel<<<256, 512, 0, stream>>>(x, w1, b1, bph, bpl, b2, u);
  for (int pass = 0; pass < 4; ++pass) {
    const int mode = (pass == 0) ? 0 : (pass < 3 ? 1 : 2);
    routing_a_kernel<<<dim3(N_IMG, 18), 256, 0, stream>>>(u, cw, bp, vsum, sp,
                                                          pass);
    routing_b_kernel<<<N_IMG, 192, 0, stream>>>(sp, v_out, probs, vsum, mode);
  }
}

// Round 5
// 1158.534 us; speedup vs baseline: 7.6895x; 1.1895x over previous
//
#include <hip/hip_runtime.h>

// ============================================================================
// CapsuleNet forward. Round 5: fused_conv was LDS-read-bound (80 b128 A-reads
// per block k-step ~ 960cyc vs 300 MFMA cyc) + 7.8e7 bank conflicts.
//   - k-split: wave = (ntile-group g, k-half kpar); nt=4/wave, half the tt
//     range each -> A-read traffic halved; LDS merge of partial acc.
//   - A stored as 4 arrays (hi/lo x ci-half), 16B rows, XOR swizzle
//     row^((row>>3)&7) -> ~2-way conflicts (free).
//   - B register prefetch (1 deep). repack_b via LDS slab. routing_a reads
//     caps_w transposed (cw_t[cap][od][k], aliases dead bph region).
// ============================================================================

#define N_IMG 512

typedef __attribute__((ext_vector_type(8))) short bf16x8;
typedef __attribute__((ext_vector_type(4))) float f32x4;
typedef __attribute__((ext_vector_type(4))) unsigned int u32x4;

__device__ __forceinline__ unsigned short f2bf(float v) {
  unsigned int uu = __float_as_uint(v);
  uu += 0x7FFF + ((uu >> 16) & 1);
  return (unsigned short)(uu >> 16);
}
__device__ __forceinline__ float bf2f(unsigned short h) {
  return __uint_as_float(((unsigned int)h) << 16);
}
__device__ __forceinline__ int swz(int row) {  // byte offset of 16B A-row
  return (row ^ ((row >> 3) & 7)) << 4;
}

// ---------------------------------------------------------------------------
// repack conv2 weights w2[256co][256ci][81rs] -> B-fragment order (hi/lo):
// Bp[n 16][ktile 656][lane 64][8], ktile = c*41+tt, rs = 2tt+lh padded to 82.
// LDS slab kills the 16x gather amplification of the direct version.
// ---------------------------------------------------------------------------
__global__ __launch_bounds__(256) void repack_b_kernel(
    const float* __restrict__ w2, unsigned short* __restrict__ bph,
    unsigned short* __restrict__ bpl) {
  __shared__ float slab[82 * 16 * 17];  // [rs][co][ci pad 17]
  const int n = blockIdx.x, c = blockIdx.y;
  const int tid = threadIdx.x;
  for (int e = tid; e < 81 * 256; e += 256) {
    const int row = e / 81;  // co*16+ci
    const int rs = e - row * 81;
    const int co = row >> 4, ci = row & 15;
    slab[(rs * 16 + co) * 17 + ci] =
        w2[((size_t)(n * 16 + co) * 256 + c * 16 + ci) * 81 + rs];
  }
  __syncthreads();
  const int lane = tid & 63;
  const int l15 = lane & 15;
  const int lh = lane >> 5;
  const int cio8 = ((lane >> 4) & 1) * 8;
  for (int tt = tid >> 6; tt < 41; tt += 4) {
    const int rs = 2 * tt + lh;
    unsigned int hw[4], lw[4];
#pragma unroll
    for (int jp = 0; jp < 4; ++jp) {
      unsigned short h2[2], l2[2];
#pragma unroll
      for (int e = 0; e < 2; ++e) {
        const int j = jp * 2 + e;
        float v = (rs < 81) ? slab[(rs * 16 + l15) * 17 + cio8 + j] : 0.0f;
        unsigned short hh = f2bf(v);
        h2[e] = hh;
        l2[e] = f2bf(v - bf2f(hh));
      }
      hw[jp] = (unsigned int)h2[0] | ((unsigned int)h2[1] << 16);
      lw[jp] = (unsigned int)l2[0] | ((unsigned int)l2[1] << 16);
    }
    const size_t off = (((size_t)n * 656 + c * 41 + tt) * 64 + lane) * 8;
    *(u32x4*)(bph + off) = (u32x4){hw[0], hw[1], hw[2], hw[3]};
    *(u32x4*)(bpl + off) = (u32x4){lw[0], lw[1], lw[2], lw[3]};
  }
}

// ---------------------------------------------------------------------------
// transpose caps_w [1152][8][160] -> cw_t [1152][160][8] for routing_a.
// ---------------------------------------------------------------------------
__global__ __launch_bounds__(160) void repack_cw_kernel(
    const float* __restrict__ cw, float* __restrict__ cwt) {
  __shared__ float t[8][160];
  const int i = blockIdx.x;
  const int od = threadIdx.x;
#pragma unroll
  for (int k = 0; k < 8; ++k) t[k][od] = cw[((size_t)i * 8 + k) * 160 + od];
  __syncthreads();
  float4 o0 = {t[0][od], t[1][od], t[2][od], t[3][od]};
  float4 o1 = {t[4][od], t[5][od], t[6][od], t[7][od]};
  float4* dst = (float4*)(cwt + ((size_t)i * 160 + od) * 8);
  dst[0] = o0;
  dst[1] = o1;
}

// ---------------------------------------------------------------------------
// Fused conv1 -> hi/lo A (swizzled) -> MFMA conv2 (k-split) -> squash.
// 256 blocks x 512 thr (8 waves). wave = (g = wid&3 -> ntiles g*4..g*4+3,
// kpar = wid>>2 -> tt half). LDS map (bytes):
//   A0h@0  A1h@12928  A0l@25856  A1l@38784   (808 rows x 16B each)
//   stg@51712 (12928 f)  img@103424 (1568 f)  w1l@109696  b1l@114880
//   total 114944. mrg@0 (81920) and sq@0 (73728) alias post-loop.
// ---------------------------------------------------------------------------
__global__ __launch_bounds__(512, 1) void fused_conv_kernel(
    const float* __restrict__ x, const float* __restrict__ w1,
    const float* __restrict__ b1, const unsigned short* __restrict__ bph,
    const unsigned short* __restrict__ bpl, const float* __restrict__ b2,
    float* __restrict__ u) {
  __shared__ __align__(16) char smem[114944];
  float* stg = (float*)(smem + 51712);   // [2][16][404]
  float* img = (float*)(smem + 103424);  // [2][784]
  float* w1l = (float*)(smem + 109696);  // [16*81]
  float* b1l = (float*)(smem + 114880);  // [16]
  float* mrg = (float*)smem;
  float* sq = (float*)smem;

  const int bp2 = blockIdx.x;
  const int tid = threadIdx.x;
  const int wid = tid >> 6;
  const int g = wid & 3;
  const int kpar = wid >> 2;
  const int lane = tid & 63;
  const int l15 = lane & 15;
  const int lq4 = lane >> 4;
  const int lqb = lq4 & 1;
  const int lh = lane >> 5;

  int rowb[5];
  bool okm[5];
#pragma unroll
  for (int mt = 0; mt < 5; ++mt) {
    const int m = mt * 16 + l15;
    okm[mt] = (m < 72);
    const int mm = okm[mt] ? m : 0;
    const int im = (mm >= 36) ? 1 : 0;
    const int p = mm - 36 * im;
    const int oy = p / 6, ox = p - 6 * oy;
    rowb[mt] = im * 400 + 40 * oy + 2 * ox;
  }

  for (int i = tid; i < 1568; i += 512) img[i] = x[bp2 * 1568 + i];
  if (tid < 16) {  // zero pad-row 800 (swizzled slot 804) in all 4 arrays
    *(int*)(smem + (tid >> 2) * 12928 + 804 * 16 + (tid & 3) * 4) = 0;
  }

  f32x4 acc[5][4];
#pragma unroll
  for (int mt = 0; mt < 5; ++mt)
#pragma unroll
    for (int nn = 0; nn < 4; ++nn) acc[mt][nn] = (f32x4){0.f, 0.f, 0.f, 0.f};

  const char* hbase = smem + lqb * 12928;
  const char* lbase = smem + 25856 + lqb * 12928;
  const int tt0 = kpar ? 21 : 0;
  const int tt1 = kpar ? 41 : 21;

  for (int c = 0; c < 16; ++c) {
    __syncthreads();  // prev MFMA reads done
    for (int i = tid; i < 1296; i += 512) w1l[i] = w1[c * 1296 + i];
    if (tid < 16) b1l[tid] = b1[c * 16 + tid];
    __syncthreads();

    // conv1: 640 tasks (ig, oy, ch); weights of own channel from LDS
    for (int t = tid; t < 640; t += 512) {
      const int ig = t / 320;
      const int rest = t - ig * 320;
      const int ch = rest & 15;
      const int oy = rest >> 4;
      const float* ib = &img[ig * 784];
      float a[20];
      const float bv1 = b1l[ch];
#pragma unroll
      for (int ox = 0; ox < 20; ++ox) a[ox] = bv1;
#pragma unroll
      for (int r = 0; r < 9; ++r) {
        float row[28];
        const float4* rp = (const float4*)&ib[(oy + r) * 28];
#pragma unroll
        for (int q = 0; q < 7; ++q) {
          float4 v4 = rp[q];
          row[4 * q + 0] = v4.x; row[4 * q + 1] = v4.y;
          row[4 * q + 2] = v4.z; row[4 * q + 3] = v4.w;
        }
#pragma unroll
        for (int s = 0; s < 9; ++s) {
          const float wval = w1l[ch * 81 + r * 9 + s];
#pragma unroll
          for (int ox = 0; ox < 20; ++ox)
            a[ox] = fmaf(row[ox + s], wval, a[ox]);
        }
      }
      float4* dst = (float4*)&stg[(ig * 16 + ch) * 404 + oy * 20];
#pragma unroll
      for (int q = 0; q < 5; ++q) {
        float4 v4;
        v4.x = fmaxf(a[4 * q + 0], 0.0f);
        v4.y = fmaxf(a[4 * q + 1], 0.0f);
        v4.z = fmaxf(a[4 * q + 2], 0.0f);
        v4.w = fmaxf(a[4 * q + 3], 0.0f);
        dst[q] = v4;
      }
    }
    __syncthreads();

    // transpose stg -> swizzled A arrays (t == row)
    for (int t = tid; t < 800; t += 512) {
      const int ig = t / 400;
      const int pos = t - ig * 400;
      const int ad = swz(t);
      unsigned int hw[8], lw[8];
#pragma unroll
      for (int jp = 0; jp < 8; ++jp) {
        unsigned short h2[2], l2[2];
#pragma unroll
        for (int e = 0; e < 2; ++e) {
          const float v = stg[(ig * 16 + jp * 2 + e) * 404 + pos];
          const unsigned short hh = f2bf(v);
          h2[e] = hh;
          l2[e] = f2bf(v - bf2f(hh));
        }
        hw[jp] = (unsigned int)h2[0] | ((unsigned int)h2[1] << 16);
        lw[jp] = (unsigned int)l2[0] | ((unsigned int)l2[1] << 16);
      }
      *(u32x4*)(smem + ad) = (u32x4){hw[0], hw[1], hw[2], hw[3]};
      *(u32x4*)(smem + 12928 + ad) = (u32x4){hw[4], hw[5], hw[6], hw[7]};
      *(u32x4*)(smem + 25856 + ad) = (u32x4){lw[0], lw[1], lw[2], lw[3]};
      *(u32x4*)(smem + 38784 + ad) = (u32x4){lw[4], lw[5], lw[6], lw[7]};
    }
    __syncthreads();

    // MFMA over this chunk, k-half [tt0,tt1)
    const unsigned short* pb[4];
    const unsigned short* pl[4];
#pragma unroll
    for (int nn = 0; nn < 4; ++nn) {
      const size_t base =
          ((size_t)(g * 4 + nn) * 656 + c * 41 + tt0) * 512 + lane * 8;
      pb[nn] = bph + base;
      pl[nn] = bpl + base;
    }
    bf16x8 cbh[4], cbl[4];
#pragma unroll
    for (int nn = 0; nn < 4; ++nn) {
      cbh[nn] = *(const bf16x8*)(pb[nn]);
      cbl[nn] = *(const bf16x8*)(pl[nn]);
    }
#pragma unroll 1
    for (int tt = tt0; tt < tt1; ++tt) {
      const int nxt = (tt + 1 < tt1) ? (tt + 1 - tt0) : (tt - tt0);
      bf16x8 nbh[4], nbl[4];
#pragma unroll
      for (int nn = 0; nn < 4; ++nn) {
        nbh[nn] = *(const bf16x8*)(pb[nn] + (size_t)nxt * 512);
        nbl[nn] = *(const bf16x8*)(pl[nn] + (size_t)nxt * 512);
      }
      const int rs = 2 * tt + lh;
      const int r = (rs * 57) >> 9;
      const int s = rs - 9 * r;
      const int rs20 = 20 * r + s;
      const bool okrs = (rs <= 80);
      bf16x8 ah[5], al[5];
#pragma unroll
      for (int mt = 0; mt < 5; ++mt) {
        const int row = (okm[mt] && okrs) ? (rowb[mt] + rs20) : 800;
        const int ad = swz(row);
        ah[mt] = *(const bf16x8*)(hbase + ad);
        al[mt] = *(const bf16x8*)(lbase + ad);
      }
#pragma unroll
      for (int mt = 0; mt < 5; ++mt) {
#pragma unroll
        for (int nn = 0; nn < 4; ++nn) {
          acc[mt][nn] = __builtin_amdgcn_mfma_f32_16x16x32_bf16(
              al[mt], cbh[nn], acc[mt][nn], 0, 0, 0);
          acc[mt][nn] = __builtin_amdgcn_mfma_f32_16x16x32_bf16(
              ah[mt], cbl[nn], acc[mt][nn], 0, 0, 0);
          acc[mt][nn] = __builtin_amdgcn_mfma_f32_16x16x32_bf16(
              ah[mt], cbh[nn], acc[mt][nn], 0, 0, 0);
        }
      }
#pragma unroll
      for (int nn = 0; nn < 4; ++nn) {
        cbh[nn] = nbh[nn];
        cbl[nn] = nbl[nn];
      }
    }
  }

  // merge k-halves, bias, store sq, squash
  __syncthreads();
  if (kpar == 1) {
#pragma unroll
    for (int mt = 0; mt < 5; ++mt)
#pragma unroll
      for (int nn = 0; nn < 4; ++nn)
        *(f32x4*)(mrg + ((((g * 5 + mt) * 4 + nn) * 64 + lane) << 2)) =
            acc[mt][nn];
  }
  __syncthreads();
  if (kpar == 0) {
#pragma unroll
    for (int mt = 0; mt < 5; ++mt)
#pragma unroll
      for (int nn = 0; nn < 4; ++nn)
        acc[mt][nn] +=
            *(const f32x4*)(mrg + ((((g * 5 + mt) * 4 + nn) * 64 + lane) << 2));
  }
  __syncthreads();
  if (kpar == 0) {
    float b2v[4];
#pragma unroll
    for (int nn = 0; nn < 4; ++nn) b2v[nn] = b2[(g * 4 + nn) * 16 + l15];
#pragma unroll
    for (int mt = 0; mt < 5; ++mt) {
#pragma unroll
      for (int i = 0; i < 4; ++i) {
        const int m = mt * 16 + lq4 * 4 + i;
        if (m < 72) {
          const int im = (m >= 36) ? 1 : 0;
          const int p36 = m - 36 * im;
#pragma unroll
          for (int nn = 0; nn < 4; ++nn) {
            sq[(im * 256 + (g * 4 + nn) * 16 + l15) * 36 + p36] =
                acc[mt][nn][i] + b2v[nn];
          }
        }
      }
    }
  }
  __syncthreads();

  for (int i = tid; i < 2304; i += 512) {
    const int ig = i / 1152;
    const int cap = i - ig * 1152;
    const int gg = cap / 36, yx = cap - 36 * gg;
    float vals[8];
    float lensq = 0.0f;
#pragma unroll
    for (int d = 0; d < 8; ++d) {
      vals[d] = sq[(ig * 256 + gg * 8 + d) * 36 + yx];
      lensq = fmaf(vals[d], vals[d], lensq);
    }
    const float len = sqrtf(lensq);
    const float scale = lensq / (1.0f + lensq) / len;
    float4* dst = (float4*)(u + ((size_t)(bp2 * 2 + ig) * 1152 + cap) * 8);
    float4 lo4, hi4;
    lo4.x = vals[0] * scale; lo4.y = vals[1] * scale;
    lo4.z = vals[2] * scale; lo4.w = vals[3] * scale;
    hi4.x = vals[4] * scale; hi4.y = vals[5] * scale;
    hi4.z = vals[6] * scale; hi4.w = vals[7] * scale;
    dst[0] = lo4; dst[1] = hi4;
  }
}

// ---------------------------------------------------------------------------
// routing pass A: recompute u_hat chunk (64x160) from cw_t (vectorized),
// b = b_prior (+ uhat.vsum, linearity), softmax, partial s.
// ---------------------------------------------------------------------------
__global__ __launch_bounds__(256) void routing_a_kernel(
    const float* __restrict__ u, const float* __restrict__ cwt,
    const float* __restrict__ b_prior, const float* __restrict__ vsum,
    float* __restrict__ s_part, int pass) {
  __shared__ float u_l[64 * 8];
  __shared__ float uhat[64 * 160];
  __shared__ float b_l[64 * 10];
  __shared__ float c_l[64 * 10];
  __shared__ float v_l[160];

  const int b = blockIdx.x;
  const int ch = blockIdx.y;
  const int cap0 = ch * 64;
  const int tid = threadIdx.x;

  {
    const float* src = u + ((size_t)b * 1152 + cap0) * 8;
    for (int i = tid; i < 512; i += 256) u_l[i] = src[i];
  }
  if (pass > 0 && tid < 160) v_l[tid] = vsum[b * 160 + tid];
  __syncthreads();

  for (int idx = tid; idx < 64 * 160; idx += 256) {
    const int i = idx / 160, od = idx - 160 * i;
    const float4* wp =
        (const float4*)(cwt + ((size_t)(cap0 + i) * 160 + od) * 8);
    const float4 wa = wp[0], wb = wp[1];
    const float4 ua = *(const float4*)&u_l[i * 8];
    const float4 ub = *(const float4*)&u_l[i * 8 + 4];
    float a = ua.x * wa.x;
    a = fmaf(ua.y, wa.y, a); a = fmaf(ua.z, wa.z, a); a = fmaf(ua.w, wa.w, a);
    a = fmaf(ub.x, wb.x, a); a = fmaf(ub.y, wb.y, a);
    a = fmaf(ub.z, wb.z, a); a = fmaf(ub.w, wb.w, a);
    uhat[idx] = a;
  }
  __syncthreads();

  for (int idx = tid; idx < 640; idx += 256) {
    const int i = idx / 10, o = idx - 10 * i;
    float bb = b_prior[(cap0 + i) * 10 + o];
    if (pass > 0) {
      float agg = 0.0f;
#pragma unroll
      for (int d = 0; d < 16; ++d)
        agg = fmaf(uhat[i * 160 + o * 16 + d], v_l[o * 16 + d], agg);
      bb += agg;
    }
    b_l[idx] = bb;
  }
  __syncthreads();

  if (tid < 64) {
    float m = -1e30f;
#pragma unroll
    for (int o = 0; o < 10; ++o) m = fmaxf(m, b_l[tid * 10 + o]);
    float e[10], sum = 0.0f;
#pragma unroll
    for (int o = 0; o < 10; ++o) {
      e[o] = __expf(b_l[tid * 10 + o] - m);
      sum += e[o];
    }
    const float inv = 1.0f / sum;
#pragma unroll
    for (int o = 0; o < 10; ++o) c_l[tid * 10 + o] = e[o] * inv;
  }
  __syncthreads();

  if (tid < 160) {
    const int o = tid / 16;
    float a = 0.0f;
    for (int i = 0; i < 64; ++i)
      a = fmaf(c_l[i * 10 + o], uhat[i * 160 + tid], a);
    s_part[((size_t)ch * N_IMG + b) * 160 + tid] = a;
  }
}

// ---------------------------------------------------------------------------
// routing pass B: reduce partials -> squash -> v, probs; vsum mode.
// ---------------------------------------------------------------------------
__global__ __launch_bounds__(192) void routing_b_kernel(
    const float* __restrict__ s_part, float* __restrict__ v_out,
    float* __restrict__ probs, float* __restrict__ vsum, int mode) {
  __shared__ float s_l[160];
  __shared__ float scale_l[10];
  __shared__ float len_l[10];
  const int b = blockIdx.x;
  const int t = threadIdx.x;
  if (t < 160) {
    float a = 0.0f;
#pragma unroll
    for (int ch = 0; ch < 18; ++ch)
      a += s_part[((size_t)ch * N_IMG + b) * 160 + t];
    s_l[t] = a;
  }
  __syncthreads();
  if (t < 10) {
    float lensq = 0.0f;
#pragma unroll
    for (int d = 0; d < 16; ++d) {
      const float xv = s_l[t * 16 + d];
      lensq = fmaf(xv, xv, lensq);
    }
    const float len = sqrtf(lensq);
    scale_l[t] = lensq / (1.0f + lensq) / len;
    len_l[t] = lensq / (1.0f + lensq);
  }
  __syncthreads();
  if (t < 160) {
    const float vv = s_l[t] * scale_l[t / 16];
    v_out[b * 160 + t] = vv;
    if (mode == 0) vsum[b * 160 + t] = vv;
    else if (mode == 1) vsum[b * 160 + t] += vv;
  }
  if (t < 10) probs[b * 10 + t] = len_l[t];
}

// ===========================================================================
extern "C" void kernel_launch(void* const* d_in, const int* in_sizes, int n_in,
                              void* d_out, int out_size, void* d_ws,
                              size_t ws_size, hipStream_t stream) {
  const float* x  = (const float*)d_in[0];
  const float* w1 = (const float*)d_in[1];
  const float* b1 = (const float*)d_in[2];
  const float* w2 = (const float*)d_in[3];
  const float* b2 = (const float*)d_in[4];
  const float* cw = (const float*)d_in[5];
  const float* bp = (const float*)d_in[6];

  float* out = (float*)d_out;
  float* v_out = out;                // [512,10,16]
  float* probs = out + N_IMG * 160;  // [512,10]

  unsigned short* bph = (unsigned short*)d_ws;          // 10.75 MB
  unsigned short* bpl = bph + (size_t)16 * 656 * 512;   // 10.75 MB
  float* u    = (float*)d_ws + 2 * 2686976;             // 18.9 MB
  float* sp   = u + (size_t)N_IMG * 1152 * 8;           //  5.9 MB
  float* vsum = sp + (size_t)18 * N_IMG * 160;          //  0.33 MB
  float* cwt  = (float*)bph;  // 5.9 MB, reuses bph AFTER fused_conv

  repack_b_kernel<<<dim3(16, 16), 256, 0, stream>>>(w2, bph, bpl);
  fused_conv_kernel<<<256, 512, 0, stream>>>(x, w1, b1, bph, bpl, b2, u);
  repack_cw_kernel<<<1152, 160, 0, stream>>>(cw, cwt);
  for (int pass = 0; pass < 4; ++pass) {
    const int mode = (pass == 0) ? 0 : (pass < 3 ? 1 : 2);
    routing_a_kernel<<<dim3(N_IMG, 18), 256, 0, stream>>>(u, cwt, bp, vsum, sp,
                                                          pass);
    routing_b_kernel<<<N_IMG, 192, 0, stream>>>(sp, v_out, probs, vsum, mode);
  }
}